// Round 5
// baseline (7195.222 us; speedup 1.0000x reference)
//
#include <hip/hip_runtime.h>
#include <cfloat>

// Problem constants (fixed by setup_inputs)
#define BATCH 128
#define NP    16384
#define NC    4096
#define MPTS  (NP + NC)   // 20480
#define SOUT  2048
#define NTHR  1024
#define KPT   20          // points per thread
#define NPAIR 10          // processed as float2 pairs: k = 2p, 2p+1

// Packed fp32 (CDNA VOP3P): 2 points per instruction, per-half IEEE
// semantics identical to the scalar __fmul_rn/__builtin_fmaf path that
// bit-matched the reference in round 3.
__device__ inline float2 pk_add(float2 a, float2 b) {
    float2 d; asm("v_pk_add_f32 %0, %1, %2" : "=v"(d) : "v"(a), "v"(b)); return d;
}
__device__ inline float2 pk_mul(float2 a, float2 b) {
    float2 d; asm("v_pk_mul_f32 %0, %1, %2" : "=v"(d) : "v"(a), "v"(b)); return d;
}
__device__ inline float2 pk_fma(float2 a, float2 b, float2 c) {
    float2 d; asm("v_pk_fma_f32 %0, %1, %2, %3" : "=v"(d) : "v"(a), "v"(b), "v"(c)); return d;
}

// 64-lane max-reduce of a u64 key at VALU speed via DPP:
// row_shr 1/2/4/8 (tree within 16-lane rows) + row_bcast15 + row_bcast31.
// Result lands in lane 63. Identity 0 is safe: all real keys are > 0.
__device__ inline void wave_max_key(unsigned int& lo, unsigned int& hi) {
#define DPP_STEP(ctrl)                                                              \
    {                                                                               \
        unsigned int lo2 = (unsigned int)__builtin_amdgcn_update_dpp(               \
            0, (int)lo, (ctrl), 0xF, 0xF, false);                                   \
        unsigned int hi2 = (unsigned int)__builtin_amdgcn_update_dpp(               \
            0, (int)hi, (ctrl), 0xF, 0xF, false);                                   \
        unsigned long long a = ((unsigned long long)hi << 32) | lo;                 \
        unsigned long long b = ((unsigned long long)hi2 << 32) | lo2;               \
        if (b > a) { lo = lo2; hi = hi2; }                                          \
    }
    DPP_STEP(0x111)  // row_shr:1
    DPP_STEP(0x112)  // row_shr:2
    DPP_STEP(0x114)  // row_shr:4
    DPP_STEP(0x118)  // row_shr:8
    DPP_STEP(0x142)  // row_bcast15
    DPP_STEP(0x143)  // row_bcast31
#undef DPP_STEP
}

// One block per batch. Each thread owns 20 points (m = k*NTHR + t) in
// registers as float2 pairs. Per step: packed distance update + running
// (val,idx) argmax, DPP wave reduce, one LDS u64 atomicMax across the 16
// waves, 2 barriers, winner writes q + output slot directly (fused gather).
//
// __launch_bounds__(1024, 4): 4 waves/EU = 16 waves/CU = exactly one block
// resident (grid is 128 blocks on 256 CUs, so >1 block/CU never happens).
// This raises the VGPR cap to 128 and eliminates the scratch spills that
// made round 4 latency-bound (WRITE_SIZE 11.3 MB -> expect ~3.1 MB).
__global__ __launch_bounds__(NTHR, 4) void fps_kernel(
    const float* __restrict__ partial,   // [B, NP, 3]
    const float* __restrict__ coarse,    // [B, 3, NC]
    float* __restrict__ out)             // [B, 3, SOUT]
{
    const int b = blockIdx.x;
    const int t = threadIdx.x;
    const int lane = t & 63;

    __shared__ float s_q[4];                   // broadcast query point
    __shared__ unsigned long long s_key[2];    // double-buffered argmax slot

    float2 x2[NPAIR], y2[NPAIR], z2[NPAIR], md2[NPAIR];

    const float* Pb = partial + (size_t)b * NP * 3;
    const float* Cb = coarse + (size_t)b * 3 * NC;

#pragma unroll
    for (int p = 0; p < NPAIR; ++p) {
        const int k0 = 2 * p;
        const int k1 = 2 * p + 1;
        const int m0 = k0 * NTHR + t;
        const int m1 = k1 * NTHR + t;
        if (k0 < 16) {  // both halves from partial ([M,3] layout)
            x2[p].x = Pb[m0 * 3 + 0]; y2[p].x = Pb[m0 * 3 + 1]; z2[p].x = Pb[m0 * 3 + 2];
            x2[p].y = Pb[m1 * 3 + 0]; y2[p].y = Pb[m1 * 3 + 1]; z2[p].y = Pb[m1 * 3 + 2];
        } else {        // both halves from coarse ([3,NC] layout)
            const int j0 = m0 - NP, j1 = m1 - NP;
            x2[p].x = Cb[0 * NC + j0]; y2[p].x = Cb[1 * NC + j0]; z2[p].x = Cb[2 * NC + j0];
            x2[p].y = Cb[0 * NC + j1]; y2[p].y = Cb[1 * NC + j1]; z2[p].y = Cb[2 * NC + j1];
        }
        md2[p].x = FLT_MAX; md2[p].y = FLT_MAX;
    }

    float* outb = out + (size_t)b * 3 * SOUT;

    // First selected index is 0 (owned by thread 0, pair 0 half .x).
    if (t == 0) {
        s_q[0] = x2[0].x; s_q[1] = y2[0].x; s_q[2] = z2[0].x;
        outb[0 * SOUT + 0] = x2[0].x;
        outb[1 * SOUT + 0] = y2[0].x;
        outb[2 * SOUT + 0] = z2[0].x;
        s_key[0] = 0ULL; s_key[1] = 0ULL;
    }
    __syncthreads();

    float qx = s_q[0], qy = s_q[1], qz = s_q[2];

    for (int s = 0; s < SOUT - 1; ++s) {
        const int cur = s & 1, nxt = cur ^ 1;
        // Negated q: x + (-q) is bit-identical to x - q.
        const float2 vnqx = {-qx, -qx}, vnqy = {-qy, -qy}, vnqz = {-qz, -qz};

        float bv = -1.0f;
        int bi = 0;
#pragma unroll
        for (int p = 0; p < NPAIR; ++p) {
            const float2 dx  = pk_add(x2[p], vnqx);
            const float2 dy  = pk_add(y2[p], vnqy);
            const float2 dz  = pk_add(z2[p], vnqz);
            const float2 dy2 = pk_mul(dy, dy);
            const float2 ts  = pk_fma(dx, dx, dy2);
            const float2 dd  = pk_fma(dz, dz, ts);
            // Reference order preserved per half: fma(dz,dz, fma(dx,dx, rn(dy*dy)))
            const float m0 = fminf(md2[p].x, dd.x);
            const float m1 = fminf(md2[p].y, dd.y);
            md2[p].x = m0; md2[p].y = m1;
            // Strict > with ascending k keeps the earliest index on ties.
            if (m0 > bv) { bv = m0; bi = 2 * p; }
            if (m1 > bv) { bv = m1; bi = 2 * p + 1; }
        }

        // Pack (value, index): float bits monotone for v>=0; ~m resolves
        // equal values to the smallest global index m = k*NTHR + t.
        unsigned int klo = ~((unsigned int)((bi << 10) | t));
        unsigned int khi = __float_as_uint(bv);
        wave_max_key(klo, khi);

        if (lane == 63) {
            atomicMax(&s_key[cur], ((unsigned long long)khi << 32) | klo);
        }
        if (t == 0) s_key[nxt] = 0ULL;  // zero the other slot for step s+1
        __syncthreads();

        const unsigned long long wk = s_key[cur];
        const unsigned int mid = ~((unsigned int)(wk & 0xFFFFFFFFULL));
        if ((mid & (NTHR - 1)) == (unsigned int)t) {
            const int kk = (int)(mid >> 10);
            float wx = 0.f, wy = 0.f, wz = 0.f;
#pragma unroll
            for (int p = 0; p < NPAIR; ++p) {
                if (p == (kk >> 1)) {
                    if (kk & 1) { wx = x2[p].y; wy = y2[p].y; wz = z2[p].y; }
                    else        { wx = x2[p].x; wy = y2[p].x; wz = z2[p].x; }
                }
            }
            s_q[0] = wx; s_q[1] = wy; s_q[2] = wz;
            const int slot = s + 1;
            outb[0 * SOUT + slot] = wx;
            outb[1 * SOUT + slot] = wy;
            outb[2 * SOUT + slot] = wz;
        }
        __syncthreads();

        qx = s_q[0]; qy = s_q[1]; qz = s_q[2];
    }
}

extern "C" void kernel_launch(void* const* d_in, const int* in_sizes, int n_in,
                              void* d_out, int out_size, void* d_ws, size_t ws_size,
                              hipStream_t stream) {
    (void)in_sizes; (void)n_in; (void)d_ws; (void)ws_size; (void)out_size;
    const float* partial = (const float*)d_in[0];
    const float* coarse  = (const float*)d_in[1];
    float* out = (float*)d_out;
    fps_kernel<<<dim3(BATCH), dim3(NTHR), 0, stream>>>(partial, coarse, out);
}

// Round 6
// 3463.610 us; speedup vs baseline: 2.0774x; 2.0774x over previous
//
#include <hip/hip_runtime.h>
#include <cfloat>

// Problem constants (fixed by setup_inputs)
#define BATCH 128
#define NP    16384
#define NC    4096
#define MPTS  (NP + NC)   // 20480
#define SOUT  2048
#define NTHR  1024
#define KPT   20          // points per thread

// One DPP max-reduce step on a u64 key split across (hi, lo) u32 regs.
// old=0 / bound_ctrl=false: invalid-source lanes contribute key 0, which is
// the identity for our max (all real keys > 0).
#define DPP_MAX_STEP(ctrl, rmask)                                                  \
    {                                                                              \
        unsigned int lo2 = (unsigned int)__builtin_amdgcn_update_dpp(              \
            0, (int)klo, (ctrl), (rmask), 0xF, false);                             \
        unsigned int hi2 = (unsigned int)__builtin_amdgcn_update_dpp(              \
            0, (int)khi, (ctrl), (rmask), 0xF, false);                             \
        const unsigned long long a =                                               \
            ((unsigned long long)khi << 32) | (unsigned long long)klo;             \
        const unsigned long long c =                                               \
            ((unsigned long long)hi2 << 32) | (unsigned long long)lo2;             \
        if (c > a) { klo = lo2; khi = hi2; }                                       \
    }

// One block per batch. Each thread owns 20 points (m = k*NTHR + t) and their
// running min_d entirely in registers. Per step: scalar bit-exact distance
// update + running (val,idx) argmax, 6-step DPP wave max-reduce (result in
// lane 63), one LDS u64 atomicMax across the 16 waves, 2 barriers, winner
// thread writes q + the output slot directly (fused gather).
//
// amdgpu_waves_per_eu(4,4): grid is 128 blocks on 256 CUs, so only one
// 16-wave block is ever resident per CU (4 waves/EU). Forcing max=4 raises
// the VGPR budget to 128 and stops the allocator from targeting 8 waves/EU
// (64 VGPRs), which spilled the 80-register point state in rounds 3-5.
__global__ __launch_bounds__(NTHR)
__attribute__((amdgpu_waves_per_eu(4, 4)))
void fps_kernel(
    const float* __restrict__ partial,   // [B, NP, 3]
    const float* __restrict__ coarse,    // [B, 3, NC]
    float* __restrict__ out)             // [B, 3, SOUT]
{
    const int b = blockIdx.x;
    const int t = threadIdx.x;
    const int lane = t & 63;

    __shared__ float s_q[4];                   // broadcast query point
    __shared__ unsigned long long s_key[2];    // double-buffered argmax slot

    float x[KPT], y[KPT], z[KPT], md[KPT];

    const float* Pb = partial + (size_t)b * NP * 3;
    const float* Cb = coarse + (size_t)b * 3 * NC;

#pragma unroll
    for (int k = 0; k < KPT; ++k) {
        const int m = k * NTHR + t;
        if (k < 16) {   // from partial ([M,3] layout)
            x[k] = Pb[m * 3 + 0];
            y[k] = Pb[m * 3 + 1];
            z[k] = Pb[m * 3 + 2];
        } else {        // from coarse ([3,NC] layout)
            const int j = m - NP;
            x[k] = Cb[0 * NC + j];
            y[k] = Cb[1 * NC + j];
            z[k] = Cb[2 * NC + j];
        }
        md[k] = FLT_MAX;
    }

    float* outb = out + (size_t)b * 3 * SOUT;

    // First selected index is 0 (owned by thread 0, slot 0).
    if (t == 0) {
        s_q[0] = x[0]; s_q[1] = y[0]; s_q[2] = z[0];
        outb[0 * SOUT + 0] = x[0];
        outb[1 * SOUT + 0] = y[0];
        outb[2 * SOUT + 0] = z[0];
        s_key[0] = 0ULL; s_key[1] = 0ULL;
    }
    __syncthreads();

    float qx = s_q[0], qy = s_q[1], qz = s_q[2];

    for (int s = 0; s < SOUT - 1; ++s) {
        const int cur = s & 1, nxt = cur ^ 1;

        float bv = -1.0f;
        int bi = 0;
#pragma unroll
        for (int k = 0; k < KPT; ++k) {
            const float dx = __fsub_rn(x[k], qx);
            const float dy = __fsub_rn(y[k], qy);
            const float dz = __fsub_rn(z[k], qz);
            // Reference-exact contraction (proven bit-exact in round 3):
            // fma(dz,dz, fma(dx,dx, rn(dy*dy)))
            const float dy2 = __fmul_rn(dy, dy);
            const float d = __builtin_fmaf(dz, dz, __builtin_fmaf(dx, dx, dy2));
            const float nmd = fminf(md[k], d);
            md[k] = nmd;
            // Strict > with ascending k keeps the earliest index on ties.
            if (nmd > bv) { bv = nmd; bi = k; }
        }

        // Pack (value, index): float bits monotone for v>=0; ~m resolves
        // equal values to the smallest global index m = k*NTHR + t.
        unsigned int klo = ~((unsigned int)((bi << 10) | t));
        unsigned int khi = __float_as_uint(bv);

        // Canonical gfx9 wave64 max-reduce to lane 63:
        // row_shr 1/2/4/8, then row_bcast15 (rows 1,3), row_bcast31 (rows 2,3).
        DPP_MAX_STEP(0x111, 0xF)  // row_shr:1
        DPP_MAX_STEP(0x112, 0xF)  // row_shr:2
        DPP_MAX_STEP(0x114, 0xF)  // row_shr:4
        DPP_MAX_STEP(0x118, 0xF)  // row_shr:8
        DPP_MAX_STEP(0x142, 0xa)  // row_bcast:15
        DPP_MAX_STEP(0x143, 0xc)  // row_bcast:31

        if (lane == 63) {
            atomicMax(&s_key[cur],
                      ((unsigned long long)khi << 32) | (unsigned long long)klo);
        }
        if (t == 0) s_key[nxt] = 0ULL;  // zero the other slot for step s+1
        __syncthreads();

        const unsigned long long wk = s_key[cur];
        const unsigned int mid = ~((unsigned int)(wk & 0xFFFFFFFFULL));
        if ((mid & (NTHR - 1)) == (unsigned int)t) {
            const int kk = (int)(mid >> 10);
            float wx = 0.f, wy = 0.f, wz = 0.f;
#pragma unroll
            for (int k = 0; k < KPT; ++k) {
                if (k == kk) { wx = x[k]; wy = y[k]; wz = z[k]; }
            }
            s_q[0] = wx; s_q[1] = wy; s_q[2] = wz;
            const int slot = s + 1;
            outb[0 * SOUT + slot] = wx;
            outb[1 * SOUT + slot] = wy;
            outb[2 * SOUT + slot] = wz;
        }
        __syncthreads();

        qx = s_q[0]; qy = s_q[1]; qz = s_q[2];
    }
}

extern "C" void kernel_launch(void* const* d_in, const int* in_sizes, int n_in,
                              void* d_out, int out_size, void* d_ws, size_t ws_size,
                              hipStream_t stream) {
    (void)in_sizes; (void)n_in; (void)d_ws; (void)ws_size; (void)out_size;
    const float* partial = (const float*)d_in[0];
    const float* coarse  = (const float*)d_in[1];
    float* out = (float*)d_out;
    fps_kernel<<<dim3(BATCH), dim3(NTHR), 0, stream>>>(partial, coarse, out);
}